// Round 1
// baseline (1337.579 us; speedup 1.0000x reference)
//
#include <hip/hip_runtime.h>
#include <hip/hip_bf16.h>
#include <stdint.h>

// TreeLSTM Fenwick reduction, 12 levels. Per level:
//   out[M,640] = Hcat[M,256] @ [U_iou(256x384) | Uf_W(256x256)] + gates
// Split-precision MFMA (A_hi*W_hi + A_lo*W_hi + A_hi*W_lo) => ~fp32 accuracy.
// v2: term-split (hi 40KB / lo 40KB) double-buffered LDS pipeline with
// global_load_lds staging (T3-min 2-phase pattern), c-loads prefetched one
// phase early, s_setprio around MFMA clusters.

#define DEV __device__ __forceinline__

typedef __attribute__((ext_vector_type(8))) short bf16x8;   // 8 bf16 = 4 VGPR
typedef __attribute__((ext_vector_type(4))) float f32x4;

typedef __attribute__((address_space(3))) uint32_t lds_u32_t;
typedef const __attribute__((address_space(1))) uint32_t glb_u32_t;

DEV float bf2f(unsigned short u) {
    union { uint32_t i; float f; } v; v.i = ((uint32_t)u) << 16; return v.f;
}
DEV unsigned short f2bf(float f) {                 // round-to-nearest-even
    union { float f; uint32_t i; } v; v.f = f;
    uint32_t u = v.i;
    return (unsigned short)((u + 0x7FFFu + ((u >> 16) & 1u)) >> 16);
}
DEV unsigned short truncbf(float f) {              // truncate (hi part of split)
    union { float f; uint32_t i; } v; v.f = f; return (unsigned short)(v.i >> 16);
}
DEV float sigm(float x) { return 1.0f / (1.0f + __expf(-x)); }
DEV float tanh_(float x) {
    x = fminf(fmaxf(x, -15.f), 15.f);
    float e = __expf(2.0f * x);
    return (e - 1.0f) / (e + 1.0f);
}
DEV float ldmix(const void* p, size_t i, int bf) {
    return bf ? bf2f(((const unsigned short*)p)[i]) : ((const float*)p)[i];
}

// Stage one 40 KB term tile (20480 shorts) global->LDS, no VGPR round trip.
// LDS dest is linear (wave-uniform base + lane*16) as global_load_lds needs.
template<int BLK>
DEV void stage_term(unsigned short* dst, const unsigned short* src, int tid) {
    constexpr int NIT = 40960 / (BLK * 16);        // 5 (BLK=512) or 10 (BLK=256)
    #pragma unroll
    for (int it = 0; it < NIT; ++it) {
        int o = (it * BLK + tid) * 8;              // short index, 16B per lane
        __builtin_amdgcn_global_load_lds((glb_u32_t*)(src + o),
                                         (lds_u32_t*)(dst + o), 16, 0, 0);
    }
}

// ---- pack W into MFMA-B fragment order, split into bf16 hi/lo; also detect
// input dtype (block-redundant) and stage fp32 biases into ws.
// Wp layout: [j(8)][term(2)][g(5)][ks(8)][lane(64)][jj(8)] shorts; per-(j,term)
// block of 20480 shorts (40 KB) is contiguous => staging is a linear copy.
// Element = W[k = ks*32 + (lane>>4)*8 + jj][n = g*128 + j*16 + (lane&15)].
__global__ void pack_w(const void* __restrict__ h_bot,
                       const void* __restrict__ U_iou, const void* __restrict__ Uf_W,
                       const void* __restrict__ b_iou, const void* __restrict__ uf_b,
                       int* __restrict__ flag_out, float* __restrict__ bias_out,
                       unsigned short* __restrict__ Wp) {
    __shared__ int total;
    const int tid = threadIdx.x;
    if (tid == 0) total = 0;
    __syncthreads();
    const unsigned short* hs = (const unsigned short*)h_bot;
    int local = 0;
    #pragma unroll
    for (int i = 0; i < 4; ++i) {
        unsigned short s = hs[tid * 4 + i];
        int e = (s >> 7) & 0xFF;
        local += (e >= 100 && e <= 134) ? 1 : 0;
    }
    atomicAdd(&total, local);
    __syncthreads();
    const int flag = (total > 820) ? 1 : 0;   // 1 = inputs are bf16

    if (blockIdx.x == 0) {
        if (tid == 0) *flag_out = flag;
        for (int i = tid; i < 384; i += 256) bias_out[i]       = ldmix(b_iou, i, flag);
        for (int i = tid; i < 256; i += 256) bias_out[384 + i] = ldmix(uf_b, i, flag);
    }

    int idx  = blockIdx.x * 256 + tid;        // 163840 total
    int j    = idx / 20480;
    int rem  = idx % 20480;
    int g    = rem / 4096;
    int rem2 = rem & 4095;
    int ks   = rem2 >> 9;
    int lane = (rem2 >> 3) & 63;
    int jj   = rem2 & 7;
    int k = ks * 32 + (lane >> 4) * 8 + jj;
    int t = j * 16 + (lane & 15);
    float w = (g < 3) ? ldmix(U_iou, (size_t)k * 384 + g * 128 + t, flag)
                      : ldmix(Uf_W,  (size_t)k * 256 + (g - 3) * 128 + t, flag);
    unsigned short hi = truncbf(w);
    unsigned short lo = f2bf(w - bf2f(hi));
    size_t base = (size_t)j * 40960;
    int fb = (g * 8 + ks) * 512 + lane * 8 + jj;
    Wp[base + fb]         = hi;               // term 0 (W_hi)
    Wp[base + 20480 + fb] = lo;               // term 1 (W_lo)
}

// IN_MODE: 0 = level0 (raw inputs, dtype per flag), 1 = bf16 hi/lo pair,
//          2 = single bf16 (LEAN). JSPLIT: j = blockIdx.y (2 phases/block).
// Phase ph = j*2 + term; term 0 = W_hi (4 MFMA/(ks,g)), term 1 = W_lo (2).
template<int IN_MODE, bool LEAN, bool FINAL, bool JSPLIT, int BLK>
__global__ __launch_bounds__(BLK, (BLK == 512 ? 4 : 2))
void level_kernel(const void* __restrict__ h_in,
                  const unsigned short* __restrict__ h_lo_in,
                  const void* __restrict__ c_in_v,
                  const unsigned short* __restrict__ Wp,
                  const int* __restrict__ flag_p,
                  const float* __restrict__ bias,
                  unsigned short* __restrict__ h_hi_out,
                  unsigned short* __restrict__ h_lo_out,
                  void* __restrict__ c_out_v,
                  void* __restrict__ final_out,
                  int M_out) {
    __shared__ __align__(16) unsigned short ldsW[2][20480];  // 2 x 40 KB ping-pong
    const int tid  = threadIdx.x;
    const int lane = tid & 63;
    const int w    = tid >> 6;
    const int ROWS = BLK / 2;                     // rows per block
    const int R0   = blockIdx.x * ROWS + w * 32;  // wave: rows R0..R0+31
    const int mrow = lane & 15;
    const int quad = lane >> 4;
    const int flag = (IN_MODE == 0 || FINAL) ? *flag_p : 0;

    const int phBeg = JSPLIT ? 2 * (int)blockIdx.y : 0;
    const int phEnd = JSPLIT ? phBeg + 2 : 16;

    // Kick off phase-0 staging immediately (critical path).
    stage_term<BLK>(ldsW[0], Wp + (size_t)phBeg * 20480, tid);

    // ---- A fragments (register-resident). Hcat k = child*128 + (ks&3)*32
    // + quad*8 + jj; frag #ks covers k in [ks*32, ks*32+32).
    bf16x8 a_hi[2][8], a_lo[2][8];
    #pragma unroll
    for (int mt = 0; mt < 2; ++mt) {
        int r = R0 + mt * 16 + mrow;
        if (r >= M_out) r = M_out - 1;            // clamp; stores are guarded
        #pragma unroll
        for (int ks = 0; ks < 8; ++ks) {
            size_t base = ((size_t)(2 * r + (ks >> 2))) * 128 + (ks & 3) * 32 + quad * 8;
            if (IN_MODE == 0) {
                if (flag) {   // bf16 inputs: hi = data, lo = 0
                    a_hi[mt][ks] = *(const bf16x8*)((const unsigned short*)h_in + base);
                    bf16x8 z;
                    #pragma unroll
                    for (int e = 0; e < 8; ++e) z[e] = 0;
                    a_lo[mt][ks] = z;
                } else {      // fp32 inputs: split on the fly
                    const float* hf = (const float*)h_in;
                    f32x4 x0 = *(const f32x4*)(hf + base);
                    f32x4 x1 = *(const f32x4*)(hf + base + 4);
                    bf16x8 hv, lv;
                    #pragma unroll
                    for (int e = 0; e < 4; ++e) {
                        float x = x0[e];
                        unsigned short hh = truncbf(x);
                        hv[e] = (short)hh; lv[e] = (short)f2bf(x - bf2f(hh));
                    }
                    #pragma unroll
                    for (int e = 0; e < 4; ++e) {
                        float x = x1[e];
                        unsigned short hh = truncbf(x);
                        hv[4 + e] = (short)hh; lv[4 + e] = (short)f2bf(x - bf2f(hh));
                    }
                    a_hi[mt][ks] = hv; a_lo[mt][ks] = lv;
                }
            } else if (IN_MODE == 1) {
                a_hi[mt][ks] = *(const bf16x8*)((const unsigned short*)h_in + base);
                a_lo[mt][ks] = *(const bf16x8*)(h_lo_in + base);
            } else {
                a_hi[mt][ks] = *(const bf16x8*)((const unsigned short*)h_in + base);
            }
        }
    }

    __syncthreads();                              // phase-0 tile resident

    f32x4 acc[5][2];
    #pragma unroll
    for (int g = 0; g < 5; ++g) {
        acc[g][0] = f32x4{0.f, 0.f, 0.f, 0.f};
        acc[g][1] = f32x4{0.f, 0.f, 0.f, 0.f};
    }
    float cpre[2][4][2];                          // c prefetch (hi phase -> lo epi)

    int cur = 0;
    #pragma unroll 1
    for (int ph = phBeg; ph < phEnd; ++ph) {
        const int j    = ph >> 1;
        const int term = ph & 1;

        // 1) issue next phase's 40 KB stage into the other buffer
        if (ph + 1 < phEnd)
            stage_term<BLK>(ldsW[cur ^ 1], Wp + (size_t)(ph + 1) * 20480, tid);

        // 2) on hi phase: issue epilogue c loads (latency hides under MFMAs)
        if (term == 0) {
            const int t = j * 16 + mrow;
            #pragma unroll
            for (int mt = 0; mt < 2; ++mt) {
                #pragma unroll
                for (int p = 0; p < 4; ++p) {
                    int r = R0 + mt * 16 + quad * 4 + p;
                    if (r >= M_out) r = M_out - 1;        // clamp; store guarded
                    size_t li = ((size_t)(2 * r)) * 128 + t;
                    size_t ri = li + 128;
                    float cl, cr;
                    if (IN_MODE == 0) {
                        cl = flag ? bf2f(((const unsigned short*)c_in_v)[li])
                                  : ((const float*)c_in_v)[li];
                        cr = flag ? bf2f(((const unsigned short*)c_in_v)[ri])
                                  : ((const float*)c_in_v)[ri];
                    } else if (IN_MODE == 1) {
                        cl = ((const float*)c_in_v)[li];
                        cr = ((const float*)c_in_v)[ri];
                    } else {
                        cl = bf2f(((const unsigned short*)c_in_v)[li]);
                        cr = bf2f(((const unsigned short*)c_in_v)[ri]);
                    }
                    cpre[mt][p][0] = cl; cpre[mt][p][1] = cr;
                }
            }
        }

        // 3) MFMA cluster from resident buffer
        const bf16x8* bufV = (const bf16x8*)ldsW[cur];
        __builtin_amdgcn_s_setprio(1);
        if (term == 0) {          // W_hi: a_hi*b (+ a_lo*b when split input)
            #pragma unroll
            for (int ks = 0; ks < 8; ++ks) {
                #pragma unroll
                for (int g = 0; g < 5; ++g) {
                    bf16x8 b = bufV[(g * 8 + ks) * 64 + lane];
                    acc[g][0] = __builtin_amdgcn_mfma_f32_16x16x32_bf16(a_hi[0][ks], b, acc[g][0], 0, 0, 0);
                    acc[g][1] = __builtin_amdgcn_mfma_f32_16x16x32_bf16(a_hi[1][ks], b, acc[g][1], 0, 0, 0);
                    if (IN_MODE != 2) {
                        acc[g][0] = __builtin_amdgcn_mfma_f32_16x16x32_bf16(a_lo[0][ks], b, acc[g][0], 0, 0, 0);
                        acc[g][1] = __builtin_amdgcn_mfma_f32_16x16x32_bf16(a_lo[1][ks], b, acc[g][1], 0, 0, 0);
                    }
                }
            }
        } else {                  // W_lo: a_hi*b only
            #pragma unroll
            for (int ks = 0; ks < 8; ++ks) {
                #pragma unroll
                for (int g = 0; g < 5; ++g) {
                    bf16x8 b = bufV[(g * 8 + ks) * 64 + lane];
                    acc[g][0] = __builtin_amdgcn_mfma_f32_16x16x32_bf16(a_hi[0][ks], b, acc[g][0], 0, 0, 0);
                    acc[g][1] = __builtin_amdgcn_mfma_f32_16x16x32_bf16(a_hi[1][ks], b, acc[g][1], 0, 0, 0);
                }
            }
        }
        __builtin_amdgcn_s_setprio(0);

        // 4) lo phase: epilogue (C/D layout col = lane&15, row = quad*4 + p)
        if (term == 1) {
            const int t = j * 16 + mrow;          // 0..127
            const float bi   = bias[t];
            const float bo   = bias[128 + t];
            const float bu   = bias[256 + t];
            const float bf1v = bias[384 + t];
            const float bf2v = bias[512 + t];
            #pragma unroll
            for (int mt = 0; mt < 2; ++mt) {
                #pragma unroll
                for (int p = 0; p < 4; ++p) {
                    int r = R0 + mt * 16 + quad * 4 + p;
                    if (r < M_out) {
                        float iv = sigm(acc[0][mt][p] + bi);
                        float ov = sigm(acc[1][mt][p] + bo);
                        float uv = tanh_(acc[2][mt][p] + bu);
                        float f1 = sigm(acc[3][mt][p] + bf1v);
                        float f2 = sigm(acc[4][mt][p] + bf2v);
                        float c = fmaf(iv, uv, fmaf(f1, cpre[mt][p][0], f2 * cpre[mt][p][1]));
                        float h = ov * tanh_(c);
                        if (FINAL) {
                            if (flag) {
                                unsigned short* o = (unsigned short*)final_out;
                                o[(size_t)r * 256 + t]       = f2bf(h);
                                o[(size_t)r * 256 + 128 + t] = f2bf(c);
                            } else {
                                float* o = (float*)final_out;
                                o[(size_t)r * 256 + t]       = h;
                                o[(size_t)r * 256 + 128 + t] = c;
                            }
                        } else if (LEAN) {
                            h_hi_out[(size_t)r * 128 + t] = f2bf(h);
                            ((unsigned short*)c_out_v)[(size_t)r * 128 + t] = f2bf(c);
                        } else {
                            unsigned short hh = truncbf(h);
                            h_hi_out[(size_t)r * 128 + t] = hh;
                            h_lo_out[(size_t)r * 128 + t] = f2bf(h - bf2f(hh));
                            ((float*)c_out_v)[(size_t)r * 128 + t] = c;
                        }
                    }
                }
            }
            #pragma unroll
            for (int g = 0; g < 5; ++g) {
                acc[g][0] = f32x4{0.f, 0.f, 0.f, 0.f};
                acc[g][1] = f32x4{0.f, 0.f, 0.f, 0.f};
            }
        }

        // 5) drain (vmcnt(0) incl. next stage) + barrier; skip after last phase
        if (ph + 1 < phEnd) __syncthreads();
        cur ^= 1;
    }
}

extern "C" void kernel_launch(void* const* d_in, const int* in_sizes, int n_in,
                              void* d_out, int out_size, void* d_ws, size_t ws_size,
                              hipStream_t stream) {
    const void* h_bot = d_in[0];
    const void* c_bot = d_in[1];
    const void* U_iou = d_in[2];
    const void* b_iou = d_in[3];
    const void* Uf_W  = d_in[4];
    const void* Uf_b  = d_in[5];
    (void)in_sizes; (void)n_in; (void)out_size;

    const int M0 = 131072;                        // level-0 output rows

    char* ws = (char*)d_ws;
    size_t off = 0;
    auto alloc = [&](size_t bytes) -> void* {
        off = (off + 255) & ~(size_t)255;
        void* p = ws + off;
        off += bytes;
        return p;
    };

    int*            flag = (int*)alloc(4);
    float*          bias = (float*)alloc(640 * 4);
    unsigned short* Wp   = (unsigned short*)alloc((size_t)327680 * 2);

    size_t full_need = off + 4096
                     + 2 * (size_t)33554432 + 2 * (size_t)16777216   // hA/hB hi+lo
                     + (size_t)67108864 + (size_t)33554432;          // cA, cB fp32
    bool full = (ws_size >= full_need);

    pack_w<<<dim3(640), dim3(256), 0, stream>>>(h_bot, U_iou, Uf_W, b_iou, Uf_b,
                                                flag, bias, Wp);

    if (full) {
        unsigned short* hAhi = (unsigned short*)alloc(33554432);
        unsigned short* hAlo = (unsigned short*)alloc(33554432);
        unsigned short* hBhi = (unsigned short*)alloc(16777216);
        unsigned short* hBlo = (unsigned short*)alloc(16777216);
        float*          cA   = (float*)alloc(67108864);
        float*          cB   = (float*)alloc(33554432);

        // l = 0: 131072 rows, 512 blocks x 512 threads, phase loop
        level_kernel<0, false, false, false, 512><<<dim3(512), dim3(512), 0, stream>>>(
            h_bot, nullptr, c_bot, Wp, flag, bias, hAhi, hAlo, cA, nullptr, M0);
        // l = 1: 65536 rows
        level_kernel<1, false, false, false, 512><<<dim3(256), dim3(512), 0, stream>>>(
            hAhi, hAlo, cA, Wp, flag, bias, hBhi, hBlo, cB, nullptr, M0 >> 1);
        // l = 2: 32768 rows, 256-thread blocks (full CU coverage)
        level_kernel<1, false, false, false, 256><<<dim3(256), dim3(256), 0, stream>>>(
            hBhi, hBlo, cB, Wp, flag, bias, hAhi, hAlo, cA, nullptr, M0 >> 2);

        const unsigned short* hi_in = hAhi;
        const unsigned short* lo_in = hAlo;
        const void*           c_in  = cA;
        for (int l = 3; l < 11; ++l) {
            int M = M0 >> l;
            unsigned short* ohi = (l & 1) ? hBhi : hAhi;
            unsigned short* olo = (l & 1) ? hBlo : hAlo;
            float*          oc  = (l & 1) ? cB : cA;
            level_kernel<1, false, false, true, 256>
                <<<dim3((M + 127) / 128, 8), dim3(256), 0, stream>>>(
                hi_in, lo_in, c_in, Wp, flag, bias, ohi, olo, oc, nullptr, M);
            hi_in = ohi; lo_in = olo; c_in = oc;
        }
        level_kernel<1, false, true, true, 256><<<dim3(1, 8), dim3(256), 0, stream>>>(
            hi_in, lo_in, c_in, Wp, flag, bias, nullptr, nullptr, nullptr, d_out, 64);
    } else {
        // LEAN fallback: single-bf16 h, bf16 c (~101 MB ws).
        unsigned short* hA = (unsigned short*)alloc(33554432);
        unsigned short* hB = (unsigned short*)alloc(16777216);
        unsigned short* cA = (unsigned short*)alloc(33554432);
        unsigned short* cB = (unsigned short*)alloc(16777216);

        level_kernel<0, true, false, false, 512><<<dim3(512), dim3(512), 0, stream>>>(
            h_bot, nullptr, c_bot, Wp, flag, bias, hA, nullptr, cA, nullptr, M0);
        level_kernel<2, true, false, false, 512><<<dim3(256), dim3(512), 0, stream>>>(
            hA, nullptr, cA, Wp, flag, bias, hB, nullptr, cB, nullptr, M0 >> 1);
        level_kernel<2, true, false, false, 256><<<dim3(256), dim3(256), 0, stream>>>(
            hB, nullptr, cB, Wp, flag, bias, hA, nullptr, cA, nullptr, M0 >> 2);

        const unsigned short* h_in = hA;
        const void*           c_in = cA;
        for (int l = 3; l < 11; ++l) {
            int M = M0 >> l;
            unsigned short* oh = (l & 1) ? hB : hA;
            unsigned short* oc = (l & 1) ? cB : cA;
            level_kernel<2, true, false, true, 256>
                <<<dim3((M + 127) / 128, 8), dim3(256), 0, stream>>>(
                h_in, nullptr, c_in, Wp, flag, bias, oh, nullptr, oc, nullptr, M);
            h_in = oh; c_in = oc;
        }
        level_kernel<2, true, true, true, 256><<<dim3(1, 8), dim3(256), 0, stream>>>(
            h_in, nullptr, c_in, Wp, flag, bias, nullptr, nullptr, nullptr, d_out, 64);
    }
}

// Round 2
// 1022.707 us; speedup vs baseline: 1.3079x; 1.3079x over previous
//
#include <hip/hip_runtime.h>
#include <hip/hip_bf16.h>
#include <stdint.h>

// TreeLSTM Fenwick reduction, 12 levels. Per level:
//   out[M,640] = Hcat[M,256] @ [U_iou(256x384) | Uf_W(256x256)] + gates
// Split-precision MFMA (A_hi*W_hi + A_lo*W_hi + A_hi*W_lo) => ~fp32 accuracy.
// Levels 0-2: 512-thread blocks, j-loop inside (A register reuse).
// Levels >=3: j-split grid (blockIdx.y = j) — one stage+compute per block.
// v3 = v1 + non-temporal hints on all streaming h/c loads+stores so the
// packed weight tiles (1.25 MB unique, re-staged by every block) stay
// L2-resident instead of being evicted by the streams.

#define DEV __device__ __forceinline__

typedef __attribute__((ext_vector_type(8))) short bf16x8;   // 8 bf16 = 4 VGPR
typedef __attribute__((ext_vector_type(4))) float f32x4;

#define NTL(p)    __builtin_nontemporal_load(p)
#define NTS(p, v) __builtin_nontemporal_store((v), (p))

DEV float bf2f(unsigned short u) {
    union { uint32_t i; float f; } v; v.i = ((uint32_t)u) << 16; return v.f;
}
DEV unsigned short f2bf(float f) {                 // round-to-nearest-even
    union { float f; uint32_t i; } v; v.f = f;
    uint32_t u = v.i;
    return (unsigned short)((u + 0x7FFFu + ((u >> 16) & 1u)) >> 16);
}
DEV unsigned short truncbf(float f) {              // truncate (hi part of split)
    union { float f; uint32_t i; } v; v.f = f; return (unsigned short)(v.i >> 16);
}
DEV float sigm(float x) { return 1.0f / (1.0f + __expf(-x)); }
DEV float tanh_(float x) {
    x = fminf(fmaxf(x, -15.f), 15.f);
    float e = __expf(2.0f * x);
    return (e - 1.0f) / (e + 1.0f);
}
DEV float ldmix(const void* p, size_t i, int bf) {
    return bf ? bf2f(((const unsigned short*)p)[i]) : ((const float*)p)[i];
}
// non-temporal variant for streaming c reads
DEV float ldmix_nt(const void* p, size_t i, int bf) {
    return bf ? bf2f(NTL((const unsigned short*)p + i))
              : NTL((const float*)p + i);
}

// ---- pack W into MFMA-B fragment order, split into bf16 hi/lo; also detect
// input dtype (block-redundant) and stage fp32 biases into ws.
// Wp layout: [j(8)][term(2)][g(5)][ks(8)][lane(64)][jj(8)] shorts; per-j block
// of 40960 shorts (80 KB) is contiguous => LDS staging is a linear copy.
// Element = W[k = ks*32 + (lane>>4)*8 + jj][n = g*128 + j*16 + (lane&15)].
__global__ void pack_w(const void* __restrict__ h_bot,
                       const void* __restrict__ U_iou, const void* __restrict__ Uf_W,
                       const void* __restrict__ b_iou, const void* __restrict__ uf_b,
                       int* __restrict__ flag_out, float* __restrict__ bias_out,
                       unsigned short* __restrict__ Wp) {
    __shared__ int total;
    const int tid = threadIdx.x;
    if (tid == 0) total = 0;
    __syncthreads();
    const unsigned short* hs = (const unsigned short*)h_bot;
    int local = 0;
    #pragma unroll
    for (int i = 0; i < 4; ++i) {
        unsigned short s = hs[tid * 4 + i];
        int e = (s >> 7) & 0xFF;
        local += (e >= 100 && e <= 134) ? 1 : 0;
    }
    atomicAdd(&total, local);
    __syncthreads();
    const int flag = (total > 820) ? 1 : 0;   // 1 = inputs are bf16

    if (blockIdx.x == 0) {
        if (tid == 0) *flag_out = flag;
        for (int i = tid; i < 384; i += 256) bias_out[i]       = ldmix(b_iou, i, flag);
        for (int i = tid; i < 256; i += 256) bias_out[384 + i] = ldmix(uf_b, i, flag);
    }

    int idx  = blockIdx.x * 256 + tid;        // 163840 total
    int j    = idx / 20480;
    int rem  = idx % 20480;
    int g    = rem / 4096;
    int rem2 = rem & 4095;
    int ks   = rem2 >> 9;
    int lane = (rem2 >> 3) & 63;
    int jj   = rem2 & 7;
    int k = ks * 32 + (lane >> 4) * 8 + jj;
    int t = j * 16 + (lane & 15);
    float w = (g < 3) ? ldmix(U_iou, (size_t)k * 384 + g * 128 + t, flag)
                      : ldmix(Uf_W,  (size_t)k * 256 + (g - 3) * 128 + t, flag);
    unsigned short hi = truncbf(w);
    unsigned short lo = f2bf(w - bf2f(hi));
    size_t base = (size_t)j * 40960;
    int fb = (g * 8 + ks) * 512 + lane * 8 + jj;
    Wp[base + fb]         = hi;               // term 0 (W_hi)
    Wp[base + 20480 + fb] = lo;               // term 1 (W_lo)
}

// IN_MODE: 0 = level0 (raw inputs, dtype per flag), 1 = bf16 hi/lo pair,
//          2 = single bf16 (LEAN). JSPLIT: j = blockIdx.y (one stage/block).
template<int IN_MODE, bool LEAN, bool FINAL, bool JSPLIT, int BLK>
__global__ __launch_bounds__(BLK, (BLK == 512 ? 4 : 2))
void level_kernel(const void* __restrict__ h_in,
                  const unsigned short* __restrict__ h_lo_in,
                  const void* __restrict__ c_in_v,
                  const unsigned short* __restrict__ Wp,
                  const int* __restrict__ flag_p,
                  const float* __restrict__ bias,
                  unsigned short* __restrict__ h_hi_out,
                  unsigned short* __restrict__ h_lo_out,
                  void* __restrict__ c_out_v,
                  void* __restrict__ final_out,
                  int M_out) {
    __shared__ __align__(16) unsigned short ldsW[40960];   // 80 KB, one j-tile
    const int tid  = threadIdx.x;
    const int lane = tid & 63;
    const int w    = tid >> 6;
    const int ROWS = BLK / 2;                     // rows per block
    const int R0   = blockIdx.x * ROWS + w * 32;  // wave: rows R0..R0+31
    const int mrow = lane & 15;
    const int quad = lane >> 4;
    const int flag = (IN_MODE == 0 || FINAL) ? *flag_p : 0;

    // ---- A fragments (register-resident). Hcat k = child*128 + (ks&3)*32
    // + quad*8 + jj; frag #ks covers k in [ks*32, ks*32+32).
    bf16x8 a_hi[2][8], a_lo[2][8];
    #pragma unroll
    for (int mt = 0; mt < 2; ++mt) {
        int r = R0 + mt * 16 + mrow;
        if (r >= M_out) r = M_out - 1;            // clamp; stores are guarded
        #pragma unroll
        for (int ks = 0; ks < 8; ++ks) {
            size_t base = ((size_t)(2 * r + (ks >> 2))) * 128 + (ks & 3) * 32 + quad * 8;
            if (IN_MODE == 0) {
                if (flag) {   // bf16 inputs: hi = data, lo = 0
                    a_hi[mt][ks] = NTL((const bf16x8*)((const unsigned short*)h_in + base));
                    bf16x8 z;
                    #pragma unroll
                    for (int e = 0; e < 8; ++e) z[e] = 0;
                    a_lo[mt][ks] = z;
                } else {      // fp32 inputs: split on the fly
                    const float* hf = (const float*)h_in;
                    f32x4 x0 = NTL((const f32x4*)(hf + base));
                    f32x4 x1 = NTL((const f32x4*)(hf + base + 4));
                    bf16x8 hv, lv;
                    #pragma unroll
                    for (int e = 0; e < 4; ++e) {
                        float x = x0[e];
                        unsigned short hh = truncbf(x);
                        hv[e] = (short)hh; lv[e] = (short)f2bf(x - bf2f(hh));
                    }
                    #pragma unroll
                    for (int e = 0; e < 4; ++e) {
                        float x = x1[e];
                        unsigned short hh = truncbf(x);
                        hv[4 + e] = (short)hh; lv[4 + e] = (short)f2bf(x - bf2f(hh));
                    }
                    a_hi[mt][ks] = hv; a_lo[mt][ks] = lv;
                }
            } else if (IN_MODE == 1) {
                a_hi[mt][ks] = NTL((const bf16x8*)((const unsigned short*)h_in + base));
                a_lo[mt][ks] = NTL((const bf16x8*)(h_lo_in + base));
            } else {
                a_hi[mt][ks] = NTL((const bf16x8*)((const unsigned short*)h_in + base));
            }
        }
    }

    const bf16x8* ldsV = (const bf16x8*)ldsW;
    const int jBeg = JSPLIT ? (int)blockIdx.y : 0;
    const int jEnd = JSPLIT ? (int)blockIdx.y + 1 : 8;

    #pragma unroll 1
    for (int j = jBeg; j < jEnd; ++j) {
        __syncthreads();                          // prior reads done
        {   // stage this j's 80 KB of B frags (hi then lo) — linear copy.
            // Wp loads stay CACHED: this is the data we want L2-resident.
            const bf16x8* src = (const bf16x8*)(Wp + (size_t)j * 40960);
            bf16x8*       dst = (bf16x8*)ldsW;
            #pragma unroll
            for (int it = tid; it < 5120; it += BLK)
                dst[it] = src[it];
        }
        __syncthreads();

        f32x4 acc[5][2];
        #pragma unroll
        for (int g = 0; g < 5; ++g) {
            acc[g][0] = f32x4{0.f, 0.f, 0.f, 0.f};
            acc[g][1] = f32x4{0.f, 0.f, 0.f, 0.f};
        }
        #pragma unroll
        for (int ks = 0; ks < 8; ++ks) {
            #pragma unroll
            for (int g = 0; g < 5; ++g) {
                bf16x8 bhi = ldsV[(g * 8 + ks) * 64 + lane];
                bf16x8 blo = ldsV[(40 + g * 8 + ks) * 64 + lane];
                acc[g][0] = __builtin_amdgcn_mfma_f32_16x16x32_bf16(a_hi[0][ks], bhi, acc[g][0], 0, 0, 0);
                acc[g][1] = __builtin_amdgcn_mfma_f32_16x16x32_bf16(a_hi[1][ks], bhi, acc[g][1], 0, 0, 0);
                if (IN_MODE != 2) {
                    acc[g][0] = __builtin_amdgcn_mfma_f32_16x16x32_bf16(a_lo[0][ks], bhi, acc[g][0], 0, 0, 0);
                    acc[g][1] = __builtin_amdgcn_mfma_f32_16x16x32_bf16(a_lo[1][ks], bhi, acc[g][1], 0, 0, 0);
                }
                acc[g][0] = __builtin_amdgcn_mfma_f32_16x16x32_bf16(a_hi[0][ks], blo, acc[g][0], 0, 0, 0);
                acc[g][1] = __builtin_amdgcn_mfma_f32_16x16x32_bf16(a_hi[1][ks], blo, acc[g][1], 0, 0, 0);
            }
        }

        // ---- epilogue: C/D layout col = lane&15, row = quad*4 + p
        const int t = j * 16 + mrow;              // 0..127
        const float bi   = bias[t];
        const float bo   = bias[128 + t];
        const float bu   = bias[256 + t];
        const float bf1v = bias[384 + t];
        const float bf2v = bias[512 + t];
        #pragma unroll
        for (int mt = 0; mt < 2; ++mt) {
            #pragma unroll
            for (int p = 0; p < 4; ++p) {
                int r = R0 + mt * 16 + quad * 4 + p;
                if (r < M_out) {
                    float iv = sigm(acc[0][mt][p] + bi);
                    float ov = sigm(acc[1][mt][p] + bo);
                    float uv = tanh_(acc[2][mt][p] + bu);
                    float f1 = sigm(acc[3][mt][p] + bf1v);
                    float f2 = sigm(acc[4][mt][p] + bf2v);
                    size_t li = ((size_t)(2 * r)) * 128 + t;
                    size_t ri = li + 128;
                    float cl, cr;
                    if (IN_MODE == 0) {
                        cl = ldmix_nt(c_in_v, li, flag);
                        cr = ldmix_nt(c_in_v, ri, flag);
                    } else if (IN_MODE == 1) {
                        cl = NTL((const float*)c_in_v + li);
                        cr = NTL((const float*)c_in_v + ri);
                    } else {
                        cl = bf2f(NTL((const unsigned short*)c_in_v + li));
                        cr = bf2f(NTL((const unsigned short*)c_in_v + ri));
                    }
                    float c = fmaf(iv, uv, fmaf(f1, cl, f2 * cr));
                    float h = ov * tanh_(c);
                    if (FINAL) {
                        if (flag) {
                            unsigned short* o = (unsigned short*)final_out;
                            NTS(o + (size_t)r * 256 + t,       f2bf(h));
                            NTS(o + (size_t)r * 256 + 128 + t, f2bf(c));
                        } else {
                            float* o = (float*)final_out;
                            NTS(o + (size_t)r * 256 + t,       h);
                            NTS(o + (size_t)r * 256 + 128 + t, c);
                        }
                    } else if (LEAN) {
                        NTS(h_hi_out + (size_t)r * 128 + t, f2bf(h));
                        NTS((unsigned short*)c_out_v + (size_t)r * 128 + t, f2bf(c));
                    } else {
                        unsigned short hh = truncbf(h);
                        NTS(h_hi_out + (size_t)r * 128 + t, hh);
                        NTS(h_lo_out + (size_t)r * 128 + t, f2bf(h - bf2f(hh)));
                        NTS((float*)c_out_v + (size_t)r * 128 + t, c);
                    }
                }
            }
        }
    }
}

extern "C" void kernel_launch(void* const* d_in, const int* in_sizes, int n_in,
                              void* d_out, int out_size, void* d_ws, size_t ws_size,
                              hipStream_t stream) {
    const void* h_bot = d_in[0];
    const void* c_bot = d_in[1];
    const void* U_iou = d_in[2];
    const void* b_iou = d_in[3];
    const void* Uf_W  = d_in[4];
    const void* Uf_b  = d_in[5];
    (void)in_sizes; (void)n_in; (void)out_size;

    const int M0 = 131072;                        // level-0 output rows

    char* ws = (char*)d_ws;
    size_t off = 0;
    auto alloc = [&](size_t bytes) -> void* {
        off = (off + 255) & ~(size_t)255;
        void* p = ws + off;
        off += bytes;
        return p;
    };

    int*            flag = (int*)alloc(4);
    float*          bias = (float*)alloc(640 * 4);
    unsigned short* Wp   = (unsigned short*)alloc((size_t)327680 * 2);

    size_t full_need = off + 4096
                     + 2 * (size_t)33554432 + 2 * (size_t)16777216   // hA/hB hi+lo
                     + (size_t)67108864 + (size_t)33554432;          // cA, cB fp32
    bool full = (ws_size >= full_need);

    pack_w<<<dim3(640), dim3(256), 0, stream>>>(h_bot, U_iou, Uf_W, b_iou, Uf_b,
                                                flag, bias, Wp);

    if (full) {
        unsigned short* hAhi = (unsigned short*)alloc(33554432);
        unsigned short* hAlo = (unsigned short*)alloc(33554432);
        unsigned short* hBhi = (unsigned short*)alloc(16777216);
        unsigned short* hBlo = (unsigned short*)alloc(16777216);
        float*          cA   = (float*)alloc(67108864);
        float*          cB   = (float*)alloc(33554432);

        // l = 0: 131072 rows, 512 blocks x 512 threads, j-loop
        level_kernel<0, false, false, false, 512><<<dim3(512), dim3(512), 0, stream>>>(
            h_bot, nullptr, c_bot, Wp, flag, bias, hAhi, hAlo, cA, nullptr, M0);
        // l = 1: 65536 rows
        level_kernel<1, false, false, false, 512><<<dim3(256), dim3(512), 0, stream>>>(
            hAhi, hAlo, cA, Wp, flag, bias, hBhi, hBlo, cB, nullptr, M0 >> 1);
        // l = 2: 32768 rows, 256-thread blocks (full CU coverage)
        level_kernel<1, false, false, false, 256><<<dim3(256), dim3(256), 0, stream>>>(
            hBhi, hBlo, cB, Wp, flag, bias, hAhi, hAlo, cA, nullptr, M0 >> 2);

        const unsigned short* hi_in = hAhi;
        const unsigned short* lo_in = hAlo;
        const void*           c_in  = cA;
        for (int l = 3; l < 11; ++l) {
            int M = M0 >> l;
            unsigned short* ohi = (l & 1) ? hBhi : hAhi;
            unsigned short* olo = (l & 1) ? hBlo : hAlo;
            float*          oc  = (l & 1) ? cB : cA;
            level_kernel<1, false, false, true, 256>
                <<<dim3((M + 127) / 128, 8), dim3(256), 0, stream>>>(
                hi_in, lo_in, c_in, Wp, flag, bias, ohi, olo, oc, nullptr, M);
            hi_in = ohi; lo_in = olo; c_in = oc;
        }
        level_kernel<1, false, true, true, 256><<<dim3(1, 8), dim3(256), 0, stream>>>(
            hi_in, lo_in, c_in, Wp, flag, bias, nullptr, nullptr, nullptr, d_out, 64);
    } else {
        // LEAN fallback: single-bf16 h, bf16 c (~101 MB ws).
        unsigned short* hA = (unsigned short*)alloc(33554432);
        unsigned short* hB = (unsigned short*)alloc(16777216);
        unsigned short* cA = (unsigned short*)alloc(33554432);
        unsigned short* cB = (unsigned short*)alloc(16777216);

        level_kernel<0, true, false, false, 512><<<dim3(512), dim3(512), 0, stream>>>(
            h_bot, nullptr, c_bot, Wp, flag, bias, hA, nullptr, cA, nullptr, M0);
        level_kernel<2, true, false, false, 512><<<dim3(256), dim3(512), 0, stream>>>(
            hA, nullptr, cA, Wp, flag, bias, hB, nullptr, cB, nullptr, M0 >> 1);
        level_kernel<2, true, false, false, 256><<<dim3(256), dim3(256), 0, stream>>>(
            hB, nullptr, cB, Wp, flag, bias, hA, nullptr, cA, nullptr, M0 >> 2);

        const unsigned short* h_in = hA;
        const void*           c_in = cA;
        for (int l = 3; l < 11; ++l) {
            int M = M0 >> l;
            unsigned short* oh = (l & 1) ? hB : hA;
            unsigned short* oc = (l & 1) ? cB : cA;
            level_kernel<2, true, false, true, 256>
                <<<dim3((M + 127) / 128, 8), dim3(256), 0, stream>>>(
                h_in, nullptr, c_in, Wp, flag, bias, oh, nullptr, oc, nullptr, M);
            h_in = oh; c_in = oc;
        }
        level_kernel<2, true, true, true, 256><<<dim3(1, 8), dim3(256), 0, stream>>>(
            h_in, nullptr, c_in, Wp, flag, bias, nullptr, nullptr, nullptr, d_out, 64);
    }
}

// Round 3
// 902.882 us; speedup vs baseline: 1.4815x; 1.1327x over previous
//
#include <hip/hip_runtime.h>
#include <hip/hip_bf16.h>
#include <stdint.h>

// TreeLSTM Fenwick reduction, 12 levels. Per level:
//   out[M,640] = Hcat[M,256] @ [U_iou(256x384) | Uf_W(256x256)] + gates
// Split-precision MFMA (A_hi*W_hi + A_lo*W_hi + A_hi*W_lo) => ~fp32 accuracy.
// v4: inter-level h/c tensors stored PLANE-MAJOR [j(8)][row][16] so every
// epilogue store is a dense full-line stream (v1/v3 stored 32B row-segments
// per j => ~2x write inflation + RMW fetches). Loads stay coalesced: each
// 16B A-fragment sits inside one 16-col plane. NT hints only on level-0
// external inputs (read-once); inter-level data stays cacheable for reuse.
// Per-block j rotation keeps all 8 weight tiles L2-hot.

#define DEV __device__ __forceinline__

typedef __attribute__((ext_vector_type(8))) short bf16x8;   // 8 bf16 = 4 VGPR
typedef __attribute__((ext_vector_type(4))) float f32x4;

#define NTL(p)    __builtin_nontemporal_load(p)

DEV float bf2f(unsigned short u) {
    union { uint32_t i; float f; } v; v.i = ((uint32_t)u) << 16; return v.f;
}
DEV unsigned short f2bf(float f) {                 // round-to-nearest-even
    union { float f; uint32_t i; } v; v.f = f;
    uint32_t u = v.i;
    return (unsigned short)((u + 0x7FFFu + ((u >> 16) & 1u)) >> 16);
}
DEV unsigned short truncbf(float f) {              // truncate (hi part of split)
    union { float f; uint32_t i; } v; v.f = f; return (unsigned short)(v.i >> 16);
}
DEV float sigm(float x) { return 1.0f / (1.0f + __expf(-x)); }
DEV float tanh_(float x) {
    x = fminf(fmaxf(x, -15.f), 15.f);
    float e = __expf(2.0f * x);
    return (e - 1.0f) / (e + 1.0f);
}
DEV float ldmix(const void* p, size_t i, int bf) {
    return bf ? bf2f(((const unsigned short*)p)[i]) : ((const float*)p)[i];
}
// non-temporal variant for streaming (read-once) external inputs
DEV float ldmix_nt(const void* p, size_t i, int bf) {
    return bf ? bf2f(NTL((const unsigned short*)p + i))
              : NTL((const float*)p + i);
}

// ---- pack W into MFMA-B fragment order, split into bf16 hi/lo; also detect
// input dtype (block-redundant) and stage fp32 biases into ws.
// Wp layout: [j(8)][term(2)][g(5)][ks(8)][lane(64)][jj(8)] shorts; per-j block
// of 40960 shorts (80 KB) is contiguous => LDS staging is a linear copy.
// Element = W[k = ks*32 + (lane>>4)*8 + jj][n = g*128 + j*16 + (lane&15)].
__global__ void pack_w(const void* __restrict__ h_bot,
                       const void* __restrict__ U_iou, const void* __restrict__ Uf_W,
                       const void* __restrict__ b_iou, const void* __restrict__ uf_b,
                       int* __restrict__ flag_out, float* __restrict__ bias_out,
                       unsigned short* __restrict__ Wp) {
    __shared__ int total;
    const int tid = threadIdx.x;
    if (tid == 0) total = 0;
    __syncthreads();
    const unsigned short* hs = (const unsigned short*)h_bot;
    int local = 0;
    #pragma unroll
    for (int i = 0; i < 4; ++i) {
        unsigned short s = hs[tid * 4 + i];
        int e = (s >> 7) & 0xFF;
        local += (e >= 100 && e <= 134) ? 1 : 0;
    }
    atomicAdd(&total, local);
    __syncthreads();
    const int flag = (total > 820) ? 1 : 0;   // 1 = inputs are bf16

    if (blockIdx.x == 0) {
        if (tid == 0) *flag_out = flag;
        for (int i = tid; i < 384; i += 256) bias_out[i]       = ldmix(b_iou, i, flag);
        for (int i = tid; i < 256; i += 256) bias_out[384 + i] = ldmix(uf_b, i, flag);
    }

    int idx  = blockIdx.x * 256 + tid;        // 163840 total
    int j    = idx / 20480;
    int rem  = idx % 20480;
    int g    = rem / 4096;
    int rem2 = rem & 4095;
    int ks   = rem2 >> 9;
    int lane = (rem2 >> 3) & 63;
    int jj   = rem2 & 7;
    int k = ks * 32 + (lane >> 4) * 8 + jj;
    int t = j * 16 + (lane & 15);
    float w = (g < 3) ? ldmix(U_iou, (size_t)k * 384 + g * 128 + t, flag)
                      : ldmix(Uf_W,  (size_t)k * 256 + (g - 3) * 128 + t, flag);
    unsigned short hi = truncbf(w);
    unsigned short lo = f2bf(w - bf2f(hi));
    size_t base = (size_t)j * 40960;
    int fb = (g * 8 + ks) * 512 + lane * 8 + jj;
    Wp[base + fb]         = hi;               // term 0 (W_hi)
    Wp[base + 20480 + fb] = lo;               // term 1 (W_lo)
}

// IN_MODE: 0 = level0 (raw row-major inputs, dtype per flag),
//          1 = plane-major bf16 hi/lo pair + fp32 c,
//          2 = plane-major single bf16 h + bf16 c (LEAN).
// Plane layout: element (row r, col t=j*16+m) lives at j*(M*16) + r*16 + m.
// JSPLIT: j = blockIdx.y (one stage/block).
template<int IN_MODE, bool LEAN, bool FINAL, bool JSPLIT, int BLK>
__global__ __launch_bounds__(BLK, (BLK == 512 ? 4 : 2))
void level_kernel(const void* __restrict__ h_in,
                  const unsigned short* __restrict__ h_lo_in,
                  const void* __restrict__ c_in_v,
                  const unsigned short* __restrict__ Wp,
                  const int* __restrict__ flag_p,
                  const float* __restrict__ bias,
                  unsigned short* __restrict__ h_hi_out,
                  unsigned short* __restrict__ h_lo_out,
                  void* __restrict__ c_out_v,
                  void* __restrict__ final_out,
                  int M_out) {
    __shared__ __align__(16) unsigned short ldsW[40960];   // 80 KB, one j-tile
    const int tid  = threadIdx.x;
    const int lane = tid & 63;
    const int w    = tid >> 6;
    const int ROWS = BLK / 2;                     // rows per block
    const int R0   = blockIdx.x * ROWS + w * 32;  // wave: rows R0..R0+31
    const int mrow = lane & 15;
    const int quad = lane >> 4;
    const int flag = (IN_MODE == 0 || FINAL) ? *flag_p : 0;

    const int    M_in   = 2 * M_out;              // input rows
    const size_t PS_in  = (size_t)M_in  * 16;     // plane stride (elements)
    const size_t PS_out = (size_t)M_out * 16;

    // ---- A fragments (register-resident). Hcat k = child*128 + (ks&3)*32
    // + quad*8 + jj; frag #ks covers k in [ks*32, ks*32+32).
    // Plane-major read: plane jpl = (ks&3)*2 + (quad>>1), offset (quad&1)*8.
    bf16x8 a_hi[2][8], a_lo[2][8];
    #pragma unroll
    for (int mt = 0; mt < 2; ++mt) {
        int r = R0 + mt * 16 + mrow;
        if (r >= M_out) r = M_out - 1;            // clamp; stores are guarded
        #pragma unroll
        for (int ks = 0; ks < 8; ++ks) {
            if (IN_MODE == 0) {
                size_t base = ((size_t)(2 * r + (ks >> 2))) * 128 + (ks & 3) * 32 + quad * 8;
                if (flag) {   // bf16 inputs: hi = data, lo = 0
                    a_hi[mt][ks] = NTL((const bf16x8*)((const unsigned short*)h_in + base));
                    bf16x8 z;
                    #pragma unroll
                    for (int e = 0; e < 8; ++e) z[e] = 0;
                    a_lo[mt][ks] = z;
                } else {      // fp32 inputs: split on the fly
                    const float* hf = (const float*)h_in;
                    f32x4 x0 = NTL((const f32x4*)(hf + base));
                    f32x4 x1 = NTL((const f32x4*)(hf + base + 4));
                    bf16x8 hv, lv;
                    #pragma unroll
                    for (int e = 0; e < 4; ++e) {
                        float x = x0[e];
                        unsigned short hh = truncbf(x);
                        hv[e] = (short)hh; lv[e] = (short)f2bf(x - bf2f(hh));
                    }
                    #pragma unroll
                    for (int e = 0; e < 4; ++e) {
                        float x = x1[e];
                        unsigned short hh = truncbf(x);
                        hv[4 + e] = (short)hh; lv[4 + e] = (short)f2bf(x - bf2f(hh));
                    }
                    a_hi[mt][ks] = hv; a_lo[mt][ks] = lv;
                }
            } else {
                int jpl = (ks & 3) * 2 + (quad >> 1);
                size_t base = (size_t)jpl * PS_in
                            + (size_t)(2 * r + (ks >> 2)) * 16 + (quad & 1) * 8;
                a_hi[mt][ks] = *(const bf16x8*)((const unsigned short*)h_in + base);
                if (IN_MODE == 1)
                    a_lo[mt][ks] = *(const bf16x8*)(h_lo_in + base);
            }
        }
    }

    const bf16x8* ldsV = (const bf16x8*)ldsW;
    const int jN = JSPLIT ? 1 : 8;

    #pragma unroll 1
    for (int jj = 0; jj < jN; ++jj) {
        // rotate j per block so all 8 weight tiles stay concurrently L2-hot
        const int j = JSPLIT ? (int)blockIdx.y : ((jj + (int)blockIdx.x) & 7);
        __syncthreads();                          // prior reads done
        {   // stage this j's 80 KB of B frags (hi then lo) — linear copy.
            const bf16x8* src = (const bf16x8*)(Wp + (size_t)j * 40960);
            bf16x8*       dst = (bf16x8*)ldsW;
            #pragma unroll
            for (int it = tid; it < 5120; it += BLK)
                dst[it] = src[it];
        }
        __syncthreads();

        f32x4 acc[5][2];
        #pragma unroll
        for (int g = 0; g < 5; ++g) {
            acc[g][0] = f32x4{0.f, 0.f, 0.f, 0.f};
            acc[g][1] = f32x4{0.f, 0.f, 0.f, 0.f};
        }
        #pragma unroll
        for (int ks = 0; ks < 8; ++ks) {
            #pragma unroll
            for (int g = 0; g < 5; ++g) {
                bf16x8 bhi = ldsV[(g * 8 + ks) * 64 + lane];
                bf16x8 blo = ldsV[(40 + g * 8 + ks) * 64 + lane];
                acc[g][0] = __builtin_amdgcn_mfma_f32_16x16x32_bf16(a_hi[0][ks], bhi, acc[g][0], 0, 0, 0);
                acc[g][1] = __builtin_amdgcn_mfma_f32_16x16x32_bf16(a_hi[1][ks], bhi, acc[g][1], 0, 0, 0);
                if (IN_MODE != 2) {
                    acc[g][0] = __builtin_amdgcn_mfma_f32_16x16x32_bf16(a_lo[0][ks], bhi, acc[g][0], 0, 0, 0);
                    acc[g][1] = __builtin_amdgcn_mfma_f32_16x16x32_bf16(a_lo[1][ks], bhi, acc[g][1], 0, 0, 0);
                }
                acc[g][0] = __builtin_amdgcn_mfma_f32_16x16x32_bf16(a_hi[0][ks], blo, acc[g][0], 0, 0, 0);
                acc[g][1] = __builtin_amdgcn_mfma_f32_16x16x32_bf16(a_hi[1][ks], blo, acc[g][1], 0, 0, 0);
            }
        }

        // ---- epilogue: C/D layout col = lane&15, row = quad*4 + p
        const int t = j * 16 + mrow;              // 0..127 (bias / FINAL col)
        const float bi   = bias[t];
        const float bo   = bias[128 + t];
        const float bu   = bias[256 + t];
        const float bf1v = bias[384 + t];
        const float bf2v = bias[512 + t];
        #pragma unroll
        for (int mt = 0; mt < 2; ++mt) {
            #pragma unroll
            for (int p = 0; p < 4; ++p) {
                int r = R0 + mt * 16 + quad * 4 + p;
                if (r < M_out) {
                    float iv = sigm(acc[0][mt][p] + bi);
                    float ov = sigm(acc[1][mt][p] + bo);
                    float uv = tanh_(acc[2][mt][p] + bu);
                    float f1 = sigm(acc[3][mt][p] + bf1v);
                    float f2 = sigm(acc[4][mt][p] + bf2v);
                    float cl, cr;
                    if (IN_MODE == 0) {
                        size_t li = ((size_t)(2 * r)) * 128 + t;  // row-major
                        cl = ldmix_nt(c_in_v, li, flag);
                        cr = ldmix_nt(c_in_v, li + 128, flag);
                    } else {
                        // plane-major: c[j][2r][mrow], c[j][2r+1][mrow]
                        size_t cb = (size_t)j * PS_in + (size_t)(2 * r) * 16 + mrow;
                        if (IN_MODE == 1) {
                            cl = ((const float*)c_in_v)[cb];
                            cr = ((const float*)c_in_v)[cb + 16];
                        } else {
                            cl = bf2f(((const unsigned short*)c_in_v)[cb]);
                            cr = bf2f(((const unsigned short*)c_in_v)[cb + 16]);
                        }
                    }
                    float c = fmaf(iv, uv, fmaf(f1, cl, f2 * cr));
                    float h = ov * tanh_(c);
                    if (FINAL) {
                        if (flag) {
                            unsigned short* o = (unsigned short*)final_out;
                            o[(size_t)r * 256 + t]       = f2bf(h);
                            o[(size_t)r * 256 + 128 + t] = f2bf(c);
                        } else {
                            float* o = (float*)final_out;
                            o[(size_t)r * 256 + t]       = h;
                            o[(size_t)r * 256 + 128 + t] = c;
                        }
                    } else {
                        size_t so = (size_t)j * PS_out + (size_t)r * 16 + mrow;
                        if (LEAN) {
                            h_hi_out[so] = f2bf(h);
                            ((unsigned short*)c_out_v)[so] = f2bf(c);
                        } else {
                            unsigned short hh = truncbf(h);
                            h_hi_out[so] = hh;
                            h_lo_out[so] = f2bf(h - bf2f(hh));
                            ((float*)c_out_v)[so] = c;
                        }
                    }
                }
            }
        }
    }
}

extern "C" void kernel_launch(void* const* d_in, const int* in_sizes, int n_in,
                              void* d_out, int out_size, void* d_ws, size_t ws_size,
                              hipStream_t stream) {
    const void* h_bot = d_in[0];
    const void* c_bot = d_in[1];
    const void* U_iou = d_in[2];
    const void* b_iou = d_in[3];
    const void* Uf_W  = d_in[4];
    const void* Uf_b  = d_in[5];
    (void)in_sizes; (void)n_in; (void)out_size;

    const int M0 = 131072;                        // level-0 output rows

    char* ws = (char*)d_ws;
    size_t off = 0;
    auto alloc = [&](size_t bytes) -> void* {
        off = (off + 255) & ~(size_t)255;
        void* p = ws + off;
        off += bytes;
        return p;
    };

    int*            flag = (int*)alloc(4);
    float*          bias = (float*)alloc(640 * 4);
    unsigned short* Wp   = (unsigned short*)alloc((size_t)327680 * 2);

    size_t full_need = off + 4096
                     + 2 * (size_t)33554432 + 2 * (size_t)16777216   // hA/hB hi+lo
                     + (size_t)67108864 + (size_t)33554432;          // cA, cB fp32
    bool full = (ws_size >= full_need);

    pack_w<<<dim3(640), dim3(256), 0, stream>>>(h_bot, U_iou, Uf_W, b_iou, Uf_b,
                                                flag, bias, Wp);

    if (full) {
        unsigned short* hAhi = (unsigned short*)alloc(33554432);
        unsigned short* hAlo = (unsigned short*)alloc(33554432);
        unsigned short* hBhi = (unsigned short*)alloc(16777216);
        unsigned short* hBlo = (unsigned short*)alloc(16777216);
        float*          cA   = (float*)alloc(67108864);
        float*          cB   = (float*)alloc(33554432);

        // l = 0: 131072 rows, 512 blocks x 512 threads, j-loop
        level_kernel<0, false, false, false, 512><<<dim3(512), dim3(512), 0, stream>>>(
            h_bot, nullptr, c_bot, Wp, flag, bias, hAhi, hAlo, cA, nullptr, M0);
        // l = 1: 65536 rows
        level_kernel<1, false, false, false, 512><<<dim3(256), dim3(512), 0, stream>>>(
            hAhi, hAlo, cA, Wp, flag, bias, hBhi, hBlo, cB, nullptr, M0 >> 1);
        // l = 2: 32768 rows, 256-thread blocks (full CU coverage)
        level_kernel<1, false, false, false, 256><<<dim3(256), dim3(256), 0, stream>>>(
            hBhi, hBlo, cB, Wp, flag, bias, hAhi, hAlo, cA, nullptr, M0 >> 2);

        const unsigned short* hi_in = hAhi;
        const unsigned short* lo_in = hAlo;
        const void*           c_in  = cA;
        for (int l = 3; l < 11; ++l) {
            int M = M0 >> l;
            unsigned short* ohi = (l & 1) ? hBhi : hAhi;
            unsigned short* olo = (l & 1) ? hBlo : hAlo;
            float*          oc  = (l & 1) ? cB : cA;
            level_kernel<1, false, false, true, 256>
                <<<dim3((M + 127) / 128, 8), dim3(256), 0, stream>>>(
                hi_in, lo_in, c_in, Wp, flag, bias, ohi, olo, oc, nullptr, M);
            hi_in = ohi; lo_in = olo; c_in = oc;
        }
        level_kernel<1, false, true, true, 256><<<dim3(1, 8), dim3(256), 0, stream>>>(
            hi_in, lo_in, c_in, Wp, flag, bias, nullptr, nullptr, nullptr, d_out, 64);
    } else {
        // LEAN fallback: single-bf16 h, bf16 c (~101 MB ws).
        unsigned short* hA = (unsigned short*)alloc(33554432);
        unsigned short* hB = (unsigned short*)alloc(16777216);
        unsigned short* cA = (unsigned short*)alloc(33554432);
        unsigned short* cB = (unsigned short*)alloc(16777216);

        level_kernel<0, true, false, false, 512><<<dim3(512), dim3(512), 0, stream>>>(
            h_bot, nullptr, c_bot, Wp, flag, bias, hA, nullptr, cA, nullptr, M0);
        level_kernel<2, true, false, false, 512><<<dim3(256), dim3(512), 0, stream>>>(
            hA, nullptr, cA, Wp, flag, bias, hB, nullptr, cB, nullptr, M0 >> 1);
        level_kernel<2, true, false, false, 256><<<dim3(256), dim3(256), 0, stream>>>(
            hB, nullptr, cB, Wp, flag, bias, hA, nullptr, cA, nullptr, M0 >> 2);

        const unsigned short* h_in = hA;
        const void*           c_in = cA;
        for (int l = 3; l < 11; ++l) {
            int M = M0 >> l;
            unsigned short* oh = (l & 1) ? hB : hA;
            unsigned short* oc = (l & 1) ? cB : cA;
            level_kernel<2, true, false, true, 256>
                <<<dim3((M + 127) / 128, 8), dim3(256), 0, stream>>>(
                h_in, nullptr, c_in, Wp, flag, bias, oh, nullptr, oc, nullptr, M);
            h_in = oh; c_in = oc;
        }
        level_kernel<2, true, true, true, 256><<<dim3(1, 8), dim3(256), 0, stream>>>(
            h_in, nullptr, c_in, Wp, flag, bias, nullptr, nullptr, nullptr, d_out, 64);
    }
}

// Round 4
// 700.380 us; speedup vs baseline: 1.9098x; 1.2891x over previous
//
#include <hip/hip_runtime.h>
#include <hip/hip_bf16.h>
#include <stdint.h>

// TreeLSTM Fenwick reduction, 12 levels. Per level:
//   out[M,640] = Hcat[M,256] @ [U_iou(256x384) | Uf_W(256x256)] + gates
// Split-precision MFMA (A_hi*W_hi + A_lo*W_hi + A_hi*W_lo) => ~fp32 accuracy.
// v5: fix spill/remat. The j-loop kernel previously held 128 VGPRs of A
// fragments under a 128-VGPR launch-bound cap => compiler spilled/remat'd
// A loads every j-iteration (hidden global traffic, the stubborn ~360MB
// fetch excess). Now MT=1 (16 rows/wave) for j-loop levels: A-state 64
// VGPRs, total ~105, fits cap, no spills. All NT hints removed (remat +
// non-allocating NT loads were toxic; 32B-chunk pattern needs L2 lines).
// Inter-level tensors stay plane-major [j(8)][row][16] (v4 win).

#define DEV __device__ __forceinline__

typedef __attribute__((ext_vector_type(8))) short bf16x8;   // 8 bf16 = 4 VGPR
typedef __attribute__((ext_vector_type(4))) float f32x4;

DEV float bf2f(unsigned short u) {
    union { uint32_t i; float f; } v; v.i = ((uint32_t)u) << 16; return v.f;
}
DEV unsigned short f2bf(float f) {                 // round-to-nearest-even
    union { float f; uint32_t i; } v; v.f = f;
    uint32_t u = v.i;
    return (unsigned short)((u + 0x7FFFu + ((u >> 16) & 1u)) >> 16);
}
DEV unsigned short truncbf(float f) {              // truncate (hi part of split)
    union { float f; uint32_t i; } v; v.f = f; return (unsigned short)(v.i >> 16);
}
DEV float sigm(float x) { return 1.0f / (1.0f + __expf(-x)); }
DEV float tanh_(float x) {
    x = fminf(fmaxf(x, -15.f), 15.f);
    float e = __expf(2.0f * x);
    return (e - 1.0f) / (e + 1.0f);
}
DEV float ldmix(const void* p, size_t i, int bf) {
    return bf ? bf2f(((const unsigned short*)p)[i]) : ((const float*)p)[i];
}

// ---- pack W into MFMA-B fragment order, split into bf16 hi/lo; also detect
// input dtype (block-redundant) and stage fp32 biases into ws.
// Wp layout: [j(8)][term(2)][g(5)][ks(8)][lane(64)][jj(8)] shorts; per-j block
// of 40960 shorts (80 KB) is contiguous => LDS staging is a linear copy.
// Element = W[k = ks*32 + (lane>>4)*8 + jj][n = g*128 + j*16 + (lane&15)].
__global__ void pack_w(const void* __restrict__ h_bot,
                       const void* __restrict__ U_iou, const void* __restrict__ Uf_W,
                       const void* __restrict__ b_iou, const void* __restrict__ uf_b,
                       int* __restrict__ flag_out, float* __restrict__ bias_out,
                       unsigned short* __restrict__ Wp) {
    __shared__ int total;
    const int tid = threadIdx.x;
    if (tid == 0) total = 0;
    __syncthreads();
    const unsigned short* hs = (const unsigned short*)h_bot;
    int local = 0;
    #pragma unroll
    for (int i = 0; i < 4; ++i) {
        unsigned short s = hs[tid * 4 + i];
        int e = (s >> 7) & 0xFF;
        local += (e >= 100 && e <= 134) ? 1 : 0;
    }
    atomicAdd(&total, local);
    __syncthreads();
    const int flag = (total > 820) ? 1 : 0;   // 1 = inputs are bf16

    if (blockIdx.x == 0) {
        if (tid == 0) *flag_out = flag;
        for (int i = tid; i < 384; i += 256) bias_out[i]       = ldmix(b_iou, i, flag);
        for (int i = tid; i < 256; i += 256) bias_out[384 + i] = ldmix(uf_b, i, flag);
    }

    int idx  = blockIdx.x * 256 + tid;        // 163840 total
    int j    = idx / 20480;
    int rem  = idx % 20480;
    int g    = rem / 4096;
    int rem2 = rem & 4095;
    int ks   = rem2 >> 9;
    int lane = (rem2 >> 3) & 63;
    int jj   = rem2 & 7;
    int k = ks * 32 + (lane >> 4) * 8 + jj;
    int t = j * 16 + (lane & 15);
    float w = (g < 3) ? ldmix(U_iou, (size_t)k * 384 + g * 128 + t, flag)
                      : ldmix(Uf_W,  (size_t)k * 256 + (g - 3) * 128 + t, flag);
    unsigned short hi = truncbf(w);
    unsigned short lo = f2bf(w - bf2f(hi));
    size_t base = (size_t)j * 40960;
    int fb = (g * 8 + ks) * 512 + lane * 8 + jj;
    Wp[base + fb]         = hi;               // term 0 (W_hi)
    Wp[base + 20480 + fb] = lo;               // term 1 (W_lo)
}

// IN_MODE: 0 = level0 (raw row-major inputs, dtype per flag),
//          1 = plane-major bf16 hi/lo pair + fp32 c,
//          2 = plane-major single bf16 h + bf16 c (LEAN).
// Plane layout: element (row r, col t=j*16+m) lives at j*(M*16) + r*16 + m.
// JSPLIT: j = blockIdx.y (one stage/block). MT: m-tiles (16-row) per wave.
template<int IN_MODE, bool LEAN, bool FINAL, bool JSPLIT, int BLK, int MT>
__global__ __launch_bounds__(BLK, (BLK == 512 ? 4 : 2))
void level_kernel(const void* __restrict__ h_in,
                  const unsigned short* __restrict__ h_lo_in,
                  const void* __restrict__ c_in_v,
                  const unsigned short* __restrict__ Wp,
                  const int* __restrict__ flag_p,
                  const float* __restrict__ bias,
                  unsigned short* __restrict__ h_hi_out,
                  unsigned short* __restrict__ h_lo_out,
                  void* __restrict__ c_out_v,
                  void* __restrict__ final_out,
                  int M_out) {
    __shared__ __align__(16) unsigned short ldsW[40960];   // 80 KB, one j-tile
    const int tid  = threadIdx.x;
    const int lane = tid & 63;
    const int w    = tid >> 6;
    const int ROWS = (BLK / 64) * MT * 16;        // rows per block
    const int R0   = blockIdx.x * ROWS + w * MT * 16;  // this wave's rows
    const int mrow = lane & 15;
    const int quad = lane >> 4;
    const int flag = (IN_MODE == 0 || FINAL) ? *flag_p : 0;

    const int    M_in   = 2 * M_out;              // input rows
    const size_t PS_in  = (size_t)M_in  * 16;     // plane stride (elements)
    const size_t PS_out = (size_t)M_out * 16;

    // ---- A fragments (register-resident). Hcat k = child*128 + (ks&3)*32
    // + quad*8 + jj; frag #ks covers k in [ks*32, ks*32+32).
    // Plane-major read: plane jpl = (ks&3)*2 + (quad>>1), offset (quad&1)*8.
    bf16x8 a_hi[MT][8], a_lo[MT][8];
    #pragma unroll
    for (int mt = 0; mt < MT; ++mt) {
        int r = R0 + mt * 16 + mrow;
        if (r >= M_out) r = M_out - 1;            // clamp; stores are guarded
        #pragma unroll
        for (int ks = 0; ks < 8; ++ks) {
            if (IN_MODE == 0) {
                size_t base = ((size_t)(2 * r + (ks >> 2))) * 128 + (ks & 3) * 32 + quad * 8;
                if (flag) {   // bf16 inputs: hi = data, lo = 0
                    a_hi[mt][ks] = *(const bf16x8*)((const unsigned short*)h_in + base);
                    bf16x8 z;
                    #pragma unroll
                    for (int e = 0; e < 8; ++e) z[e] = 0;
                    a_lo[mt][ks] = z;
                } else {      // fp32 inputs: split on the fly
                    const float* hf = (const float*)h_in;
                    f32x4 x0 = *(const f32x4*)(hf + base);
                    f32x4 x1 = *(const f32x4*)(hf + base + 4);
                    bf16x8 hv, lv;
                    #pragma unroll
                    for (int e = 0; e < 4; ++e) {
                        float x = x0[e];
                        unsigned short hh = truncbf(x);
                        hv[e] = (short)hh; lv[e] = (short)f2bf(x - bf2f(hh));
                    }
                    #pragma unroll
                    for (int e = 0; e < 4; ++e) {
                        float x = x1[e];
                        unsigned short hh = truncbf(x);
                        hv[4 + e] = (short)hh; lv[4 + e] = (short)f2bf(x - bf2f(hh));
                    }
                    a_hi[mt][ks] = hv; a_lo[mt][ks] = lv;
                }
            } else {
                int jpl = (ks & 3) * 2 + (quad >> 1);
                size_t base = (size_t)jpl * PS_in
                            + (size_t)(2 * r + (ks >> 2)) * 16 + (quad & 1) * 8;
                a_hi[mt][ks] = *(const bf16x8*)((const unsigned short*)h_in + base);
                if (IN_MODE == 1)
                    a_lo[mt][ks] = *(const bf16x8*)(h_lo_in + base);
            }
        }
    }

    const bf16x8* ldsV = (const bf16x8*)ldsW;
    const int jN = JSPLIT ? 1 : 8;

    #pragma unroll 1
    for (int jj = 0; jj < jN; ++jj) {
        // rotate j per block so all 8 weight tiles stay concurrently L2-hot
        const int j = JSPLIT ? (int)blockIdx.y : ((jj + (int)blockIdx.x) & 7);
        __syncthreads();                          // prior reads done
        {   // stage this j's 80 KB of B frags (hi then lo) — linear copy.
            const bf16x8* src = (const bf16x8*)(Wp + (size_t)j * 40960);
            bf16x8*       dst = (bf16x8*)ldsW;
            #pragma unroll
            for (int it = tid; it < 5120; it += BLK)
                dst[it] = src[it];
        }
        __syncthreads();

        f32x4 acc[5][MT];
        #pragma unroll
        for (int g = 0; g < 5; ++g)
            #pragma unroll
            for (int mt = 0; mt < MT; ++mt)
                acc[g][mt] = f32x4{0.f, 0.f, 0.f, 0.f};
        #pragma unroll
        for (int ks = 0; ks < 8; ++ks) {
            #pragma unroll
            for (int g = 0; g < 5; ++g) {
                bf16x8 bhi = ldsV[(g * 8 + ks) * 64 + lane];
                bf16x8 blo = ldsV[(40 + g * 8 + ks) * 64 + lane];
                #pragma unroll
                for (int mt = 0; mt < MT; ++mt) {
                    acc[g][mt] = __builtin_amdgcn_mfma_f32_16x16x32_bf16(a_hi[mt][ks], bhi, acc[g][mt], 0, 0, 0);
                    if (IN_MODE != 2)
                        acc[g][mt] = __builtin_amdgcn_mfma_f32_16x16x32_bf16(a_lo[mt][ks], bhi, acc[g][mt], 0, 0, 0);
                    acc[g][mt] = __builtin_amdgcn_mfma_f32_16x16x32_bf16(a_hi[mt][ks], blo, acc[g][mt], 0, 0, 0);
                }
            }
        }

        // ---- epilogue: C/D layout col = lane&15, row = quad*4 + p
        const int t = j * 16 + mrow;              // 0..127 (bias / FINAL col)
        const float bi   = bias[t];
        const float bo   = bias[128 + t];
        const float bu   = bias[256 + t];
        const float bf1v = bias[384 + t];
        const float bf2v = bias[512 + t];
        #pragma unroll
        for (int mt = 0; mt < MT; ++mt) {
            #pragma unroll
            for (int p = 0; p < 4; ++p) {
                int r = R0 + mt * 16 + quad * 4 + p;
                if (r < M_out) {
                    float iv = sigm(acc[0][mt][p] + bi);
                    float ov = sigm(acc[1][mt][p] + bo);
                    float uv = tanh_(acc[2][mt][p] + bu);
                    float f1 = sigm(acc[3][mt][p] + bf1v);
                    float f2 = sigm(acc[4][mt][p] + bf2v);
                    float cl, cr;
                    if (IN_MODE == 0) {
                        size_t li = ((size_t)(2 * r)) * 128 + t;  // row-major
                        cl = ldmix(c_in_v, li, flag);
                        cr = ldmix(c_in_v, li + 128, flag);
                    } else {
                        // plane-major: c[j][2r][mrow], c[j][2r+1][mrow]
                        size_t cb = (size_t)j * PS_in + (size_t)(2 * r) * 16 + mrow;
                        if (IN_MODE == 1) {
                            cl = ((const float*)c_in_v)[cb];
                            cr = ((const float*)c_in_v)[cb + 16];
                        } else {
                            cl = bf2f(((const unsigned short*)c_in_v)[cb]);
                            cr = bf2f(((const unsigned short*)c_in_v)[cb + 16]);
                        }
                    }
                    float c = fmaf(iv, uv, fmaf(f1, cl, f2 * cr));
                    float h = ov * tanh_(c);
                    if (FINAL) {
                        if (flag) {
                            unsigned short* o = (unsigned short*)final_out;
                            o[(size_t)r * 256 + t]       = f2bf(h);
                            o[(size_t)r * 256 + 128 + t] = f2bf(c);
                        } else {
                            float* o = (float*)final_out;
                            o[(size_t)r * 256 + t]       = h;
                            o[(size_t)r * 256 + 128 + t] = c;
                        }
                    } else {
                        size_t so = (size_t)j * PS_out + (size_t)r * 16 + mrow;
                        if (LEAN) {
                            h_hi_out[so] = f2bf(h);
                            ((unsigned short*)c_out_v)[so] = f2bf(c);
                        } else {
                            unsigned short hh = truncbf(h);
                            h_hi_out[so] = hh;
                            h_lo_out[so] = f2bf(h - bf2f(hh));
                            ((float*)c_out_v)[so] = c;
                        }
                    }
                }
            }
        }
    }
}

extern "C" void kernel_launch(void* const* d_in, const int* in_sizes, int n_in,
                              void* d_out, int out_size, void* d_ws, size_t ws_size,
                              hipStream_t stream) {
    const void* h_bot = d_in[0];
    const void* c_bot = d_in[1];
    const void* U_iou = d_in[2];
    const void* b_iou = d_in[3];
    const void* Uf_W  = d_in[4];
    const void* Uf_b  = d_in[5];
    (void)in_sizes; (void)n_in; (void)out_size;

    const int M0 = 131072;                        // level-0 output rows

    char* ws = (char*)d_ws;
    size_t off = 0;
    auto alloc = [&](size_t bytes) -> void* {
        off = (off + 255) & ~(size_t)255;
        void* p = ws + off;
        off += bytes;
        return p;
    };

    int*            flag = (int*)alloc(4);
    float*          bias = (float*)alloc(640 * 4);
    unsigned short* Wp   = (unsigned short*)alloc((size_t)327680 * 2);

    size_t full_need = off + 4096
                     + 2 * (size_t)33554432 + 2 * (size_t)16777216   // hA/hB hi+lo
                     + (size_t)67108864 + (size_t)33554432;          // cA, cB fp32
    bool full = (ws_size >= full_need);

    pack_w<<<dim3(640), dim3(256), 0, stream>>>(h_bot, U_iou, Uf_W, b_iou, Uf_b,
                                                flag, bias, Wp);

    if (full) {
        unsigned short* hAhi = (unsigned short*)alloc(33554432);
        unsigned short* hAlo = (unsigned short*)alloc(33554432);
        unsigned short* hBhi = (unsigned short*)alloc(16777216);
        unsigned short* hBlo = (unsigned short*)alloc(16777216);
        float*          cA   = (float*)alloc(67108864);
        float*          cB   = (float*)alloc(33554432);

        // j-loop levels: MT=1 (128 rows/block, no spills)
        level_kernel<0, false, false, false, 512, 1><<<dim3(1024), dim3(512), 0, stream>>>(
            h_bot, nullptr, c_bot, Wp, flag, bias, hAhi, hAlo, cA, nullptr, M0);
        level_kernel<1, false, false, false, 512, 1><<<dim3(512), dim3(512), 0, stream>>>(
            hAhi, hAlo, cA, Wp, flag, bias, hBhi, hBlo, cB, nullptr, M0 >> 1);
        level_kernel<1, false, false, false, 512, 1><<<dim3(256), dim3(512), 0, stream>>>(
            hBhi, hBlo, cB, Wp, flag, bias, hAhi, hAlo, cA, nullptr, M0 >> 2);

        const unsigned short* hi_in = hAhi;
        const unsigned short* lo_in = hAlo;
        const void*           c_in  = cA;
        for (int l = 3; l < 11; ++l) {
            int M = M0 >> l;
            unsigned short* ohi = (l & 1) ? hBhi : hAhi;
            unsigned short* olo = (l & 1) ? hBlo : hAlo;
            float*          oc  = (l & 1) ? cB : cA;
            level_kernel<1, false, false, true, 256, 2>
                <<<dim3((M + 127) / 128, 8), dim3(256), 0, stream>>>(
                hi_in, lo_in, c_in, Wp, flag, bias, ohi, olo, oc, nullptr, M);
            hi_in = ohi; lo_in = olo; c_in = oc;
        }
        level_kernel<1, false, true, true, 256, 2><<<dim3(1, 8), dim3(256), 0, stream>>>(
            hi_in, lo_in, c_in, Wp, flag, bias, nullptr, nullptr, nullptr, d_out, 64);
    } else {
        // LEAN fallback: single-bf16 h, bf16 c (~101 MB ws).
        unsigned short* hA = (unsigned short*)alloc(33554432);
        unsigned short* hB = (unsigned short*)alloc(16777216);
        unsigned short* cA = (unsigned short*)alloc(33554432);
        unsigned short* cB = (unsigned short*)alloc(16777216);

        level_kernel<0, true, false, false, 512, 1><<<dim3(1024), dim3(512), 0, stream>>>(
            h_bot, nullptr, c_bot, Wp, flag, bias, hA, nullptr, cA, nullptr, M0);
        level_kernel<2, true, false, false, 512, 1><<<dim3(512), dim3(512), 0, stream>>>(
            hA, nullptr, cA, Wp, flag, bias, hB, nullptr, cB, nullptr, M0 >> 1);
        level_kernel<2, true, false, false, 512, 1><<<dim3(256), dim3(512), 0, stream>>>(
            hB, nullptr, cB, Wp, flag, bias, hA, nullptr, cA, nullptr, M0 >> 2);

        const unsigned short* h_in = hA;
        const void*           c_in = cA;
        for (int l = 3; l < 11; ++l) {
            int M = M0 >> l;
            unsigned short* oh = (l & 1) ? hB : hA;
            unsigned short* oc = (l & 1) ? cB : cA;
            level_kernel<2, true, false, true, 256, 2>
                <<<dim3((M + 127) / 128, 8), dim3(256), 0, stream>>>(
                h_in, nullptr, c_in, Wp, flag, bias, oh, nullptr, oc, nullptr, M);
            h_in = oh; c_in = oc;
        }
        level_kernel<2, true, true, true, 256, 2><<<dim3(1, 8), dim3(256), 0, stream>>>(
            h_in, nullptr, c_in, Wp, flag, bias, nullptr, nullptr, nullptr, d_out, 64);
    }
}